// Round 19
// baseline (201.662 us; speedup 1.0000x reference)
//
#include <hip/hip_runtime.h>
#include <math.h>

#define KNN_EPS 1e-8f
// Spatial grid: domain [0,256)^3, cell h=16 -> 16^3 = 4096 cells.
#define GH 16.0f
#define GC 16
#define NCELLS (GC * GC * GC)
#define MARGIN 1.0f   // >> max |noisy_d - true_d| (~0.05) -> safe pruning
#define CAPR 64       // ref bucket slots/cell (Poisson(4.9); P(>=64)~1e-40)
#define CAPQ 192      // query slots/cell: counts ~8*Poisson(4.88) (C=8 cluster)

// ---------------------------------------------------------------------------
// Validated arithmetic (round 8, absmax 0.0547). DO NOT change roundings.
// Selection: (d, idx) lexicographic min-3 -- order-independent AND mergeable;
// bit-identical across r10-r18 restructures.
//
// r12-r18 lesson: every BLOCK-COOPERATIVE scan (LDS staging + barriers +
// merge) stalls ~80% on correlated barrier waits; ILP accumulators spill.
// r9 lesson: barrier-free waves with wave-uniform candidate loads scalarize
// (VGPR=8/SGPR=64) and reach VALUBusy 72%. This round: ONE WAVE PER CELL,
// no LDS, no barriers, lane = query, candidate stream wave-uniform.
// ---------------------------------------------------------------------------

__device__ __forceinline__ int cell_coord(float v) {
    int c = (int)floorf(v * (1.0f / GH));
    return min(max(c, 0), GC - 1);
}

__global__ void fused_scatter_kernel(
    const float* __restrict__ xyz1, int n1,
    const float* __restrict__ xyz2,
    const float* __restrict__ motion, int n2, int C,
    int* __restrict__ counts, int* __restrict__ qcounts,
    float4* __restrict__ rbuck, float4* __restrict__ qbuck,
    float4* __restrict__ refspill, int* __restrict__ rsn,
    float4* __restrict__ qspill, int* __restrict__ qsn)
{
#pragma clang fp contract(off)
    int i = blockIdx.x * blockDim.x + threadIdx.x;
    if (i < n1) {
        float x = xyz1[3 * i + 0];
        float y = xyz1[3 * i + 1];
        float z = xyz1[3 * i + 2];
        int cid = (cell_coord(z) * GC + cell_coord(y)) * GC + cell_coord(x);
        int pos = atomicAdd(&counts[cid], 1);
        float4 v = make_float4(x, y, z, __int_as_float(i));
        if (pos < CAPR) rbuck[cid * CAPR + pos] = v;
        else { int sp = atomicAdd(rsn, 1); refspill[sp] = v; }
    }
    int nq = n2 * C;
    if (i < nq) {
        int n = i / C;
        float qx = xyz2[3 * n + 0] + motion[3 * i + 0];   // validated adds
        float qy = xyz2[3 * n + 1] + motion[3 * i + 1];
        float qz = xyz2[3 * n + 2] + motion[3 * i + 2];
        int cid = (cell_coord(qz) * GC + cell_coord(qy)) * GC + cell_coord(qx);
        int pos = atomicAdd(&qcounts[cid], 1);
        float4 v = make_float4(qx, qy, qz, __int_as_float(i));
        if (pos < CAPQ) qbuck[cid * CAPQ + pos] = v;
        else { int sp = atomicAdd(qsn, 1); qspill[sp] = v; }
    }
}

// (d, idx)-lexicographic insert: order-independent == validated stable scan.
__device__ __forceinline__ void top3_insert_lex(float d, int j,
                                                float& bd0, float& bd1, float& bd2,
                                                int& bi0, int& bi1, int& bi2) {
    if (d < bd2 || (d == bd2 && j < bi2)) {
        if (d < bd1 || (d == bd1 && j < bi1)) {
            bd2 = bd1; bi2 = bi1;
            if (d < bd0 || (d == bd0 && j < bi0)) {
                bd1 = bd0; bi1 = bi0;
                bd0 = d;   bi0 = j;
            } else {
                bd1 = d;   bi1 = j;
            }
        } else {
            bd2 = d;       bi2 = j;
        }
    }
}

// Validated candidate evaluation (round 8 roundings, rsq recomputed bit-equal)
__device__ __forceinline__ void eval_candidate(
    float4 r, float qx, float qy, float qz, float qsq,
    float& bd0, float& bd1, float& bd2, int& bi0, int& bi1, int& bi2) {
    int ridx = __float_as_int(r.w);
    float rsq = r.x * r.x + r.y * r.y;
    rsq = rsq + r.z * r.z;
    float t = fmaf(qz, r.z, fmaf(qy, r.y, qx * r.x));
    float h = qsq + rsq;
    float d = fmaxf(fmaf(-2.0f, t, h), 0.0f);
    top3_insert_lex(d, ridx, bd0, bd1, bd2, bi0, bi1, bi2);
}

// Rigorous certification radius after scanning cell-rings <= rho.
__device__ __forceinline__ float cert_radius(float qx, float qy, float qz,
                                             int icx, int icy, int icz, int rho) {
    float R = INFINITY;
    if (icx - rho > 0)      R = fminf(R, qx - (float)(icx - rho) * GH);
    if (icx + rho < GC - 1) R = fminf(R, (float)(icx + rho + 1) * GH - qx);
    if (icy - rho > 0)      R = fminf(R, qy - (float)(icy - rho) * GH);
    if (icy + rho < GC - 1) R = fminf(R, (float)(icy + rho + 1) * GH - qy);
    if (icz - rho > 0)      R = fminf(R, qz - (float)(icz - rho) * GH);
    if (icz + rho < GC - 1) R = fminf(R, (float)(icz + rho + 1) * GH - qz);
    return R;
}

// Validated epilogue (round 8) -> writes out[qid]
__device__ __forceinline__ void epilogue_store(
    float bd0, float bd1, float bd2, int bi0, int bi1, int bi2,
    int qid, int C, const float* __restrict__ point1, float* __restrict__ out) {
#pragma clang fp contract(off)
    float dd0 = bd0 + KNN_EPS;
    float dd1 = bd1 + KNN_EPS;
    float dd2 = bd2 + KNN_EPS;
    float w0 = 1.0f / dd0;
    float w1 = 1.0f / dd1;
    float w2 = 1.0f / dd2;
    float s  = w0 + w1;
    s = s + w2;
    float m = fmaxf(s, 3.0f);
    w0 = w0 / m;
    w1 = w1 / m;
    w2 = w2 / m;
    const int c = qid - (qid / C) * C;
    float p0 = point1[bi0 * C + c];
    float p1 = point1[bi1 * C + c];
    float p2 = point1[bi2 * C + c];
    float acc = w0 * p0 + w1 * p1;
    acc = acc + w2 * p2;
    out[qid] = acc;
}

// Full ring search for ONE query (rare paths: spill, escalation).
__device__ void ring_search_from(float qx, float qy, float qz, float qsq,
                                 int rho0,
                                 const float4* __restrict__ rbuck,
                                 const int* __restrict__ counts, int rspn,
                                 const float4* __restrict__ refspill,
                                 float& bd0, float& bd1, float& bd2,
                                 int& bi0, int& bi1, int& bi2) {
    const int icx = cell_coord(qx);
    const int icy = cell_coord(qy);
    const int icz = cell_coord(qz);
    if (rho0 == 0)
        for (int k = 0; k < rspn; ++k)
            eval_candidate(refspill[k], qx, qy, qz, qsq, bd0, bd1, bd2, bi0, bi1, bi2);
    for (int rho = rho0; rho < GC; ++rho) {
        for (int dz = -rho; dz <= rho; ++dz) {
            int cz = icz + dz;
            if (cz < 0 || cz >= GC) continue;
            int adz = (dz < 0) ? -dz : dz;
            for (int dy = -rho; dy <= rho; ++dy) {
                int cy = icy + dy;
                if (cy < 0 || cy >= GC) continue;
                int ady = (dy < 0) ? -dy : dy;
                int step = (adz == rho || ady == rho || rho == 0) ? 1 : 2 * rho;
                for (int dx = -rho; dx <= rho; dx += step) {
                    int cx = icx + dx;
                    if (cx < 0 || cx >= GC) continue;
                    int cid = (cz * GC + cy) * GC + cx;
                    int e = min(counts[cid], CAPR);
                    for (int s = 0; s < e; ++s)
                        eval_candidate(rbuck[cid * CAPR + s], qx, qy, qz, qsq,
                                       bd0, bd1, bd2, bi0, bi1, bi2);
                }
            }
        }
        float Rr = cert_radius(qx, qy, qz, icx, icy, icz, rho);
        if (bd2 + MARGIN <= Rr * Rr) break;  // Rr=INF also breaks
    }
}

// ONE WAVE PER CELL, no LDS, no barriers. 256-thread blocks hold 4
// independent waves (cell = blockIdx*4 + wave). Lane = query; the 27-cell
// candidate stream is wave-uniform (broadcast loads, uniform trip counts).
// Each lane privately runs eval -> cert -> escalation -> epilogue.
__global__ __launch_bounds__(256) void knn_wave_kernel(
    const float4* __restrict__ rbuck,
    const int*   __restrict__ counts,
    const float4* __restrict__ refspill,
    const int*   __restrict__ rsn,
    const float4* __restrict__ qbuck,
    const int*   __restrict__ qcounts,
    const float* __restrict__ point1,
    float* __restrict__ out,
    int C)
{
#pragma clang fp contract(off)
    const int wave = threadIdx.x >> 6;
    const int lane = threadIdx.x & 63;
    const int cell = blockIdx.x * 4 + wave;   // grid = NCELLS/4 blocks

    const int qn = min(qcounts[cell], CAPQ);
    if (qn == 0) return;                      // per-wave exit; no barriers
    const int rspn = *rsn;
    const int qbase = cell * CAPQ;

    const int icx = cell & (GC - 1);
    const int icy = (cell >> 4) & (GC - 1);
    const int icz = cell >> 8;

    for (int it = 0; it * 64 < qn; ++it) {
        const int qo = it * 64 + lane;
        const bool active = qo < qn;
        float4 Q = qbuck[qbase + (active ? qo : 0)];
        const float qx = Q.x, qy = Q.y, qz = Q.z;
        const int qid = __float_as_int(Q.w);
        float qsq = qx * qx + qy * qy;
        qsq = qsq + qz * qz;

        float bd0 = INFINITY, bd1 = INFINITY, bd2 = INFINITY;
        int   bi0 = 0,        bi1 = 0,        bi2 = 0;

        // 27 neighbor cells; ALL control flow + addresses wave-uniform
        for (int dz = -1; dz <= 1; ++dz) {
            int cz = icz + dz;
            if (cz < 0 || cz >= GC) continue;
            for (int dy = -1; dy <= 1; ++dy) {
                int cy = icy + dy;
                if (cy < 0 || cy >= GC) continue;
                int rowb = (cz * GC + cy) * GC;
                for (int dx = -1; dx <= 1; ++dx) {
                    int cx = icx + dx;
                    if (cx < 0 || cx >= GC) continue;
                    int cid = rowb + cx;
                    int e = min(counts[cid], CAPR);
                    const float4* p = rbuck + (size_t)cid * CAPR;
                    int k = 0;
                    for (; k + 4 <= e; k += 4) {   // 4 independent broadcast loads
                        float4 c0 = p[k + 0];
                        float4 c1 = p[k + 1];
                        float4 c2 = p[k + 2];
                        float4 c3 = p[k + 3];
                        eval_candidate(c0, qx, qy, qz, qsq, bd0, bd1, bd2, bi0, bi1, bi2);
                        eval_candidate(c1, qx, qy, qz, qsq, bd0, bd1, bd2, bi0, bi1, bi2);
                        eval_candidate(c2, qx, qy, qz, qsq, bd0, bd1, bd2, bi0, bi1, bi2);
                        eval_candidate(c3, qx, qy, qz, qsq, bd0, bd1, bd2, bi0, bi1, bi2);
                    }
                    for (; k < e; ++k)
                        eval_candidate(p[k], qx, qy, qz, qsq, bd0, bd1, bd2, bi0, bi1, bi2);
                }
            }
        }

        // spilled refs (normally zero-trip, uniform)
        for (int k2 = 0; k2 < rspn; ++k2)
            eval_candidate(refspill[k2], qx, qy, qz, qsq,
                           bd0, bd1, bd2, bi0, bi1, bi2);

        // rigorous ring-1 certification; rare per-lane escalation
        float R = cert_radius(qx, qy, qz, icx, icy, icz, 1);
        if (!(bd2 + MARGIN <= R * R)) {
            ring_search_from(qx, qy, qz, qsq, 2, rbuck, counts, 0, refspill,
                             bd0, bd1, bd2, bi0, bi1, bi2);
        }

        if (active)
            epilogue_store(bd0, bd1, bd2, bi0, bi1, bi2, qid, C, point1, out);
    }
}

// Spilled queries: parallel ring search (normally zero work).
__global__ __launch_bounds__(256) void qspill_kernel(
    const float4* __restrict__ qspill, const int* __restrict__ qsn,
    const float4* __restrict__ rbuck, const int* __restrict__ counts,
    const float4* __restrict__ refspill, const int* __restrict__ rsn,
    const float* __restrict__ point1, float* __restrict__ out, int C)
{
#pragma clang fp contract(off)
    const int nsp = *qsn;
    const int rspn = *rsn;
    for (int s = blockIdx.x * blockDim.x + threadIdx.x; s < nsp;
         s += gridDim.x * blockDim.x) {
        float4 Q = qspill[s];
        const float qx = Q.x, qy = Q.y, qz = Q.z;
        const int qid = __float_as_int(Q.w);
        float qsq = qx * qx + qy * qy;
        qsq = qsq + qz * qz;
        float bd0 = INFINITY, bd1 = INFINITY, bd2 = INFINITY;
        int   bi0 = 0,        bi1 = 0,        bi2 = 0;
        ring_search_from(qx, qy, qz, qsq, 0, rbuck, counts, rspn, refspill,
                         bd0, bd1, bd2, bi0, bi1, bi2);
        epilogue_store(bd0, bd1, bd2, bi0, bi1, bi2, qid, C, point1, out);
    }
}

extern "C" void kernel_launch(void* const* d_in, const int* in_sizes, int n_in,
                              void* d_out, int out_size, void* d_ws, size_t ws_size,
                              hipStream_t stream) {
    const float* xyz1   = (const float*)d_in[0];
    const float* point1 = (const float*)d_in[1];
    const float* xyz2   = (const float*)d_in[2];
    const float* motion = (const float*)d_in[3];
    float* out = (float*)d_out;

    const int n1 = in_sizes[0] / 3;
    const int n2 = in_sizes[2] / 3;
    const int C  = in_sizes[1] / n1;
    const int nq = n2 * C;

    // ws layout (~20 MB): rbuck | qbuck | refspill | qspill | zero-zone
    char* ws = (char*)d_ws;
    size_t off = 0;
    auto alloc = [&](size_t bytes) {
        char* p = ws + off;
        off = (off + bytes + 255) & ~(size_t)255;
        return p;
    };
    float4* rbuck    = (float4*)alloc((size_t)NCELLS * CAPR * 16);
    float4* qbuck    = (float4*)alloc((size_t)NCELLS * CAPQ * 16);
    float4* refspill = (float4*)alloc((size_t)n1 * 16);
    float4* qspill   = (float4*)alloc((size_t)nq * 16);
    int*    zero     = (int*)alloc((size_t)(2 * NCELLS + 2) * 4);
    int* counts  = zero;
    int* qcounts = zero + NCELLS;
    int* rsn     = zero + 2 * NCELLS;
    int* qsn     = zero + 2 * NCELLS + 1;

    const int nmax = (n1 > nq) ? n1 : nq;

    hipMemsetAsync(zero, 0, (size_t)(2 * NCELLS + 2) * 4, stream);
    fused_scatter_kernel<<<(nmax + 255) / 256, 256, 0, stream>>>(
        xyz1, n1, xyz2, motion, n2, C,
        counts, qcounts, rbuck, qbuck, refspill, rsn, qspill, qsn);
    knn_wave_kernel<<<NCELLS / 4, 256, 0, stream>>>(
        rbuck, counts, refspill, rsn, qbuck, qcounts, point1, out, C);
    qspill_kernel<<<4, 256, 0, stream>>>(
        qspill, qsn, rbuck, counts, refspill, rsn, point1, out, C);
}

// Round 20
// 194.087 us; speedup vs baseline: 1.0390x; 1.0390x over previous
//
#include <hip/hip_runtime.h>
#include <math.h>

#define KNN_EPS 1e-8f
// Spatial grid: domain [0,256)^3, cell h=16 -> 16^3 = 4096 cells.
#define GH 16.0f
#define GC 16
#define NCELLS (GC * GC * GC)
#define MARGIN 1.0f   // >> max |noisy_d - true_d| (~0.05) -> safe pruning
#define CAPR 64       // ref bucket slots/cell (Poisson(4.9); P(>=64)~1e-40)
#define CAPQ 192      // query slots/cell: counts ~8*Poisson(4.88) (C=8 cluster)

// ---------------------------------------------------------------------------
// Validated arithmetic (round 8, absmax 0.0547). DO NOT change roundings.
// Selection: (d, idx) lexicographic min-3 -- order-independent AND mergeable;
// bit-identical across r10-r19 restructures.
//
// r19 lesson: the serial per-cell counts[cid] load (27 wave-uniform L2
// round-trips) was the stall. This round gathers all 27 counts in ONE
// predicated load (lanes 0-26) and broadcasts via __shfl -- the cell loop
// becomes memory-free, and candidate loads can overlap across cells.
// ---------------------------------------------------------------------------

__device__ __forceinline__ int cell_coord(float v) {
    int c = (int)floorf(v * (1.0f / GH));
    return min(max(c, 0), GC - 1);
}

__global__ void fused_scatter_kernel(
    const float* __restrict__ xyz1, int n1,
    const float* __restrict__ xyz2,
    const float* __restrict__ motion, int n2, int C,
    int* __restrict__ counts, int* __restrict__ qcounts,
    float4* __restrict__ rbuck, float4* __restrict__ qbuck,
    float4* __restrict__ refspill, int* __restrict__ rsn,
    float4* __restrict__ qspill, int* __restrict__ qsn)
{
#pragma clang fp contract(off)
    int i = blockIdx.x * blockDim.x + threadIdx.x;
    if (i < n1) {
        float x = xyz1[3 * i + 0];
        float y = xyz1[3 * i + 1];
        float z = xyz1[3 * i + 2];
        int cid = (cell_coord(z) * GC + cell_coord(y)) * GC + cell_coord(x);
        int pos = atomicAdd(&counts[cid], 1);
        float4 v = make_float4(x, y, z, __int_as_float(i));
        if (pos < CAPR) rbuck[cid * CAPR + pos] = v;
        else { int sp = atomicAdd(rsn, 1); refspill[sp] = v; }
    }
    int nq = n2 * C;
    if (i < nq) {
        int n = i / C;
        float qx = xyz2[3 * n + 0] + motion[3 * i + 0];   // validated adds
        float qy = xyz2[3 * n + 1] + motion[3 * i + 1];
        float qz = xyz2[3 * n + 2] + motion[3 * i + 2];
        int cid = (cell_coord(qz) * GC + cell_coord(qy)) * GC + cell_coord(qx);
        int pos = atomicAdd(&qcounts[cid], 1);
        float4 v = make_float4(qx, qy, qz, __int_as_float(i));
        if (pos < CAPQ) qbuck[cid * CAPQ + pos] = v;
        else { int sp = atomicAdd(qsn, 1); qspill[sp] = v; }
    }
}

// (d, idx)-lexicographic insert: order-independent == validated stable scan.
__device__ __forceinline__ void top3_insert_lex(float d, int j,
                                                float& bd0, float& bd1, float& bd2,
                                                int& bi0, int& bi1, int& bi2) {
    if (d < bd2 || (d == bd2 && j < bi2)) {
        if (d < bd1 || (d == bd1 && j < bi1)) {
            bd2 = bd1; bi2 = bi1;
            if (d < bd0 || (d == bd0 && j < bi0)) {
                bd1 = bd0; bi1 = bi0;
                bd0 = d;   bi0 = j;
            } else {
                bd1 = d;   bi1 = j;
            }
        } else {
            bd2 = d;       bi2 = j;
        }
    }
}

// Validated candidate evaluation (round 8 roundings, rsq recomputed bit-equal)
__device__ __forceinline__ void eval_candidate(
    float4 r, float qx, float qy, float qz, float qsq,
    float& bd0, float& bd1, float& bd2, int& bi0, int& bi1, int& bi2) {
    int ridx = __float_as_int(r.w);
    float rsq = r.x * r.x + r.y * r.y;
    rsq = rsq + r.z * r.z;
    float t = fmaf(qz, r.z, fmaf(qy, r.y, qx * r.x));
    float h = qsq + rsq;
    float d = fmaxf(fmaf(-2.0f, t, h), 0.0f);
    top3_insert_lex(d, ridx, bd0, bd1, bd2, bi0, bi1, bi2);
}

// Rigorous certification radius after scanning cell-rings <= rho.
__device__ __forceinline__ float cert_radius(float qx, float qy, float qz,
                                             int icx, int icy, int icz, int rho) {
    float R = INFINITY;
    if (icx - rho > 0)      R = fminf(R, qx - (float)(icx - rho) * GH);
    if (icx + rho < GC - 1) R = fminf(R, (float)(icx + rho + 1) * GH - qx);
    if (icy - rho > 0)      R = fminf(R, qy - (float)(icy - rho) * GH);
    if (icy + rho < GC - 1) R = fminf(R, (float)(icy + rho + 1) * GH - qy);
    if (icz - rho > 0)      R = fminf(R, qz - (float)(icz - rho) * GH);
    if (icz + rho < GC - 1) R = fminf(R, (float)(icz + rho + 1) * GH - qz);
    return R;
}

// Validated epilogue (round 8) -> writes out[qid]
__device__ __forceinline__ void epilogue_store(
    float bd0, float bd1, float bd2, int bi0, int bi1, int bi2,
    int qid, int C, const float* __restrict__ point1, float* __restrict__ out) {
#pragma clang fp contract(off)
    float dd0 = bd0 + KNN_EPS;
    float dd1 = bd1 + KNN_EPS;
    float dd2 = bd2 + KNN_EPS;
    float w0 = 1.0f / dd0;
    float w1 = 1.0f / dd1;
    float w2 = 1.0f / dd2;
    float s  = w0 + w1;
    s = s + w2;
    float m = fmaxf(s, 3.0f);
    w0 = w0 / m;
    w1 = w1 / m;
    w2 = w2 / m;
    const int c = qid - (qid / C) * C;
    float p0 = point1[bi0 * C + c];
    float p1 = point1[bi1 * C + c];
    float p2 = point1[bi2 * C + c];
    float acc = w0 * p0 + w1 * p1;
    acc = acc + w2 * p2;
    out[qid] = acc;
}

// Full ring search for ONE query (rare paths: spill, escalation).
__device__ void ring_search_from(float qx, float qy, float qz, float qsq,
                                 int rho0,
                                 const float4* __restrict__ rbuck,
                                 const int* __restrict__ counts, int rspn,
                                 const float4* __restrict__ refspill,
                                 float& bd0, float& bd1, float& bd2,
                                 int& bi0, int& bi1, int& bi2) {
    const int icx = cell_coord(qx);
    const int icy = cell_coord(qy);
    const int icz = cell_coord(qz);
    if (rho0 == 0)
        for (int k = 0; k < rspn; ++k)
            eval_candidate(refspill[k], qx, qy, qz, qsq, bd0, bd1, bd2, bi0, bi1, bi2);
    for (int rho = rho0; rho < GC; ++rho) {
        for (int dz = -rho; dz <= rho; ++dz) {
            int cz = icz + dz;
            if (cz < 0 || cz >= GC) continue;
            int adz = (dz < 0) ? -dz : dz;
            for (int dy = -rho; dy <= rho; ++dy) {
                int cy = icy + dy;
                if (cy < 0 || cy >= GC) continue;
                int ady = (dy < 0) ? -dy : dy;
                int step = (adz == rho || ady == rho || rho == 0) ? 1 : 2 * rho;
                for (int dx = -rho; dx <= rho; dx += step) {
                    int cx = icx + dx;
                    if (cx < 0 || cx >= GC) continue;
                    int cid = (cz * GC + cy) * GC + cx;
                    int e = min(counts[cid], CAPR);
                    for (int s = 0; s < e; ++s)
                        eval_candidate(rbuck[cid * CAPR + s], qx, qy, qz, qsq,
                                       bd0, bd1, bd2, bi0, bi1, bi2);
                }
            }
        }
        float Rr = cert_radius(qx, qy, qz, icx, icy, icz, rho);
        if (bd2 + MARGIN <= Rr * Rr) break;  // Rr=INF also breaks
    }
}

// ONE WAVE PER CELL, no LDS, no barriers. All 27 neighbor counts gathered by
// ONE predicated load (lanes 0-26) then broadcast via __shfl -> the cell loop
// is memory-free and candidate loads overlap across cells. The extra block
// (blockIdx == NCELLS/4) grid-strides the rare query-spill list.
__global__ __launch_bounds__(256) void knn_wave_kernel(
    const float4* __restrict__ rbuck,
    const int*   __restrict__ counts,
    const float4* __restrict__ refspill,
    const int*   __restrict__ rsn,
    const float4* __restrict__ qbuck,
    const int*   __restrict__ qcounts,
    const float4* __restrict__ qspill,
    const int*   __restrict__ qsn,
    const float* __restrict__ point1,
    float* __restrict__ out,
    int C)
{
#pragma clang fp contract(off)
    const int wave = threadIdx.x >> 6;
    const int lane = threadIdx.x & 63;
    const int cell = blockIdx.x * 4 + wave;

    if (cell >= NCELLS) {   // spill waves (normally zero work)
        const int nsp = *qsn;
        if (nsp == 0) return;
        const int rspn = *rsn;
        for (int s = (cell - NCELLS) * 64 + lane; s < nsp; s += 4 * 64) {
            float4 Q = qspill[s];
            float qsq = Q.x * Q.x + Q.y * Q.y;
            qsq = qsq + Q.z * Q.z;
            float bd0 = INFINITY, bd1 = INFINITY, bd2 = INFINITY;
            int   bi0 = 0,        bi1 = 0,        bi2 = 0;
            ring_search_from(Q.x, Q.y, Q.z, qsq, 0, rbuck, counts, rspn, refspill,
                             bd0, bd1, bd2, bi0, bi1, bi2);
            epilogue_store(bd0, bd1, bd2, bi0, bi1, bi2,
                           __float_as_int(Q.w), C, point1, out);
        }
        return;
    }

    const int qn = min(qcounts[cell], CAPQ);
    if (qn == 0) return;                      // per-wave exit; no barriers
    const int rspn = *rsn;
    const int qbase = cell * CAPQ;

    const int icx = cell & (GC - 1);
    const int icy = (cell >> 4) & (GC - 1);
    const int icz = cell >> 8;

    // ONE gather: lane t (t<27) loads neighbor t's count; broadcast by shfl.
    int mcid = 0, mcnt = 0;
    if (lane < 27) {
        int dz = lane / 9 - 1, dy = (lane / 3) % 3 - 1, dx = lane % 3 - 1;
        int cz = icz + dz, cy = icy + dy, cx = icx + dx;
        if (cz >= 0 && cz < GC && cy >= 0 && cy < GC && cx >= 0 && cx < GC) {
            mcid = (cz * GC + cy) * GC + cx;
            mcnt = min(counts[mcid], CAPR);
        }
    }

    for (int it = 0; it * 64 < qn; ++it) {
        const int qo = it * 64 + lane;
        const bool active = qo < qn;
        float4 Q = qbuck[qbase + (active ? qo : 0)];
        const float qx = Q.x, qy = Q.y, qz = Q.z;
        const int qid = __float_as_int(Q.w);
        float qsq = qx * qx + qy * qy;
        qsq = qsq + qz * qz;

        float bd0 = INFINITY, bd1 = INFINITY, bd2 = INFINITY;
        int   bi0 = 0,        bi1 = 0,        bi2 = 0;

        // 27 neighbor cells; counts/cids from registers via shfl (no memory)
        for (int c = 0; c < 27; ++c) {
            const int e = __shfl(mcnt, c);
            if (e == 0) continue;
            const int cidc = __shfl(mcid, c);
            const float4* p = rbuck + (size_t)cidc * CAPR;
            int k = 0;
            for (; k + 4 <= e; k += 4) {   // 4 independent broadcast loads
                float4 c0 = p[k + 0];
                float4 c1 = p[k + 1];
                float4 c2 = p[k + 2];
                float4 c3 = p[k + 3];
                eval_candidate(c0, qx, qy, qz, qsq, bd0, bd1, bd2, bi0, bi1, bi2);
                eval_candidate(c1, qx, qy, qz, qsq, bd0, bd1, bd2, bi0, bi1, bi2);
                eval_candidate(c2, qx, qy, qz, qsq, bd0, bd1, bd2, bi0, bi1, bi2);
                eval_candidate(c3, qx, qy, qz, qsq, bd0, bd1, bd2, bi0, bi1, bi2);
            }
            for (; k < e; ++k)
                eval_candidate(p[k], qx, qy, qz, qsq, bd0, bd1, bd2, bi0, bi1, bi2);
        }

        // spilled refs (normally zero-trip, uniform)
        for (int k2 = 0; k2 < rspn; ++k2)
            eval_candidate(refspill[k2], qx, qy, qz, qsq,
                           bd0, bd1, bd2, bi0, bi1, bi2);

        // rigorous ring-1 certification; rare per-lane escalation
        float R = cert_radius(qx, qy, qz, icx, icy, icz, 1);
        if (!(bd2 + MARGIN <= R * R)) {
            ring_search_from(qx, qy, qz, qsq, 2, rbuck, counts, 0, refspill,
                             bd0, bd1, bd2, bi0, bi1, bi2);
        }

        if (active)
            epilogue_store(bd0, bd1, bd2, bi0, bi1, bi2, qid, C, point1, out);
    }
}

extern "C" void kernel_launch(void* const* d_in, const int* in_sizes, int n_in,
                              void* d_out, int out_size, void* d_ws, size_t ws_size,
                              hipStream_t stream) {
    const float* xyz1   = (const float*)d_in[0];
    const float* point1 = (const float*)d_in[1];
    const float* xyz2   = (const float*)d_in[2];
    const float* motion = (const float*)d_in[3];
    float* out = (float*)d_out;

    const int n1 = in_sizes[0] / 3;
    const int n2 = in_sizes[2] / 3;
    const int C  = in_sizes[1] / n1;
    const int nq = n2 * C;

    // ws layout (~20 MB): rbuck | qbuck | refspill | qspill | zero-zone
    char* ws = (char*)d_ws;
    size_t off = 0;
    auto alloc = [&](size_t bytes) {
        char* p = ws + off;
        off = (off + bytes + 255) & ~(size_t)255;
        return p;
    };
    float4* rbuck    = (float4*)alloc((size_t)NCELLS * CAPR * 16);
    float4* qbuck    = (float4*)alloc((size_t)NCELLS * CAPQ * 16);
    float4* refspill = (float4*)alloc((size_t)n1 * 16);
    float4* qspill   = (float4*)alloc((size_t)nq * 16);
    int*    zero     = (int*)alloc((size_t)(2 * NCELLS + 2) * 4);
    int* counts  = zero;
    int* qcounts = zero + NCELLS;
    int* rsn     = zero + 2 * NCELLS;
    int* qsn     = zero + 2 * NCELLS + 1;

    const int nmax = (n1 > nq) ? n1 : nq;

    hipMemsetAsync(zero, 0, (size_t)(2 * NCELLS + 2) * 4, stream);
    fused_scatter_kernel<<<(nmax + 255) / 256, 256, 0, stream>>>(
        xyz1, n1, xyz2, motion, n2, C,
        counts, qcounts, rbuck, qbuck, refspill, rsn, qspill, qsn);
    knn_wave_kernel<<<NCELLS / 4 + 1, 256, 0, stream>>>(
        rbuck, counts, refspill, rsn, qbuck, qcounts, qspill, qsn,
        point1, out, C);
}